// Round 6
// baseline (545.336 us; speedup 1.0000x reference)
//
#include <hip/hip_runtime.h>
#include <hip/hip_bf16.h>

#define IN_CH 512
#define OUT_CH 512
#define HW 64
#define BATCH 16
#define WEIGHT_GAIN 0.014731391274719739f    // 1/sqrt(512*9)
#define MOD_WEIGHT_GAIN 0.04419417382415922f // 1/sqrt(512)

// padded NHWC xs buffer: [B][66][66][512] bf16
#define PAD_W 66
#define XS_PIX_STRIDE 512

typedef __attribute__((ext_vector_type(8))) short frag8;
typedef __attribute__((ext_vector_type(4))) float f32x4;
typedef __attribute__((ext_vector_type(16))) float f32x16;

// ---------------- style[b][i] = (sum_j w[b][j]*mw[i][j])*g + mb[i] ----------------
__global__ void style_kernel(const float* __restrict__ w, const float* __restrict__ mw,
                             const float* __restrict__ mb, float* __restrict__ style) {
    const int gw = (blockIdx.x * 256 + threadIdx.x) >> 6;  // 0..8191
    const int lane = threadIdx.x & 63;
    const int b = gw >> 9;
    const int i = gw & 511;
    const float4* mwp = (const float4*)(mw + (size_t)i * 512 + lane * 8);
    const float4* wp  = (const float4*)(w + (size_t)b * 512 + lane * 8);
    float4 m0 = mwp[0], m1 = mwp[1];
    float4 w0 = wp[0],  w1 = wp[1];
    float s = m0.x * w0.x + m0.y * w0.y + m0.z * w0.z + m0.w * w0.w
            + m1.x * w1.x + m1.y * w1.y + m1.z * w1.z + m1.w * w1.w;
#pragma unroll
    for (int off = 32; off > 0; off >>= 1) s += __shfl_down(s, off, 64);
    if (lane == 0) style[(size_t)b * 512 + i] = s * MOD_WEIGHT_GAIN + mb[i];
}

// ---------------- wsq[o][i] = G^2 * sum_kk weight^2 ; wbf[kk][o][i] = bf16(weight) ----
__global__ void wprep_kernel(const float* __restrict__ weight, float* __restrict__ wsq,
                             __hip_bfloat16* __restrict__ wbf) {
    const int idx = blockIdx.x * 256 + threadIdx.x;   // 0..262143 = o*512+i
    const float* wp = weight + idx * 9;
    float s = 0.f;
#pragma unroll
    for (int kk = 0; kk < 9; ++kk) {
        float v = wp[kk];
        s += v * v;
        wbf[kk * 262144 + idx] = __float2bfloat16(v);
    }
    wsq[idx] = s * (WEIGHT_GAIN * WEIGHT_GAIN);
}

// ---------------- sc[b][o] = G * rsqrt(sum_i style^2 * wsq + 1e-8) -------------------
__global__ void demod_kernel(const float* __restrict__ style, const float* __restrict__ wsq,
                             float* __restrict__ sc) {
    const int gw = (blockIdx.x * 256 + threadIdx.x) >> 6;  // 0..8191
    const int lane = threadIdx.x & 63;
    const int b = gw >> 9;
    const int o = gw & 511;
    const float4* wq = (const float4*)(wsq + (size_t)o * 512 + lane * 8);
    const float4* st = (const float4*)(style + (size_t)b * 512 + lane * 8);
    float4 q0 = wq[0], q1 = wq[1];
    float4 s0 = st[0], s1 = st[1];
    float acc = q0.x * s0.x * s0.x + q0.y * s0.y * s0.y + q0.z * s0.z * s0.z + q0.w * s0.w * s0.w
              + q1.x * s1.x * s1.x + q1.y * s1.y * s1.y + q1.z * s1.z * s1.z + q1.w * s1.w * s1.w;
#pragma unroll
    for (int off = 32; off > 0; off >>= 1) acc += __shfl_down(acc, off, 64);
    if (lane == 0) sc[(size_t)b * 512 + o] = rsqrtf(acc + 1e-8f) * WEIGHT_GAIN;
}

// ---------------- xs_pad[b][y+1][x+1][i] = bf16(style[b][i] * x[b][i][y][x]) ---------
// blockIdx.x == 64 blocks handle the zero pad ring (fused border kernel).
__global__ void xs_kernel(const float* __restrict__ x, const float* __restrict__ style,
                          __hip_bfloat16* __restrict__ xsp) {
    const int b = blockIdx.z;
    const int t = threadIdx.x;
    if (blockIdx.x == 64) {
        const int g = blockIdx.y;
        const int wv = t >> 6, lane = t & 63;
        for (int k = wv; k < 65; k += 4) {
            const int p = g * 65 + k;    // 0..259
            int row, col;
            if (p < 66)       { row = 0;            col = p; }
            else if (p < 132) { row = 65;           col = p - 66; }
            else if (p < 196) { row = p - 132 + 1;  col = 0; }
            else              { row = p - 196 + 1;  col = 65; }
            uint4* dst = (uint4*)(xsp + (((size_t)b * PAD_W + row) * PAD_W + col) * XS_PIX_STRIDE);
            dst[lane] = uint4{0, 0, 0, 0};
        }
        return;
    }
    const int y = blockIdx.x;            // image row 0..63
    const int lane = t & 63;             // pixel x
    const int j0 = (blockIdx.y * 4 + (t >> 6)) * 32;   // channel group of 32

    const float* xb = x + (((size_t)b * 512 + j0) * 64 + y) * 64 + lane;
    const float* stb = style + (size_t)b * 512 + j0;
    __hip_bfloat16* dst = xsp + (((size_t)b * PAD_W + (y + 1)) * PAD_W + (lane + 1)) * XS_PIX_STRIDE + j0;

    union { __hip_bfloat16 h[32]; uint4 u[4]; } pk;
#pragma unroll
    for (int k = 0; k < 32; ++k) {
        float v = xb[(size_t)k * 4096];
        pk.h[k] = __float2bfloat16(v * stb[k]);
    }
#pragma unroll
    for (int q = 0; q < 4; ++q) ((uint4*)dst)[q] = pk.u[q];
}

// ---------------- conv: implicit GEMM, 8-phase 256x256, 32x32x16 MFMA --------------
// Identical skeleton to the 274us round-3 kernel (phases, staging, vmcnt(6), region
// algebra). ONLY change: MFMA shape 16x16x32 -> 32x32x16 (ubench 2382 vs 2075 TF,
// half the MFMA instruction count). Wave tile 128x64 = 4x2 tiles of 32x32, BK=64 =
// 4 k-slices of 16. A-frag: row=lane&31, k=(lane>>5)*8..+8 (contiguous 16B). B-frag
// symmetric on the [pixel][k] LDS tile. C/D: col=lane&31, row=(reg&3)+8*(reg>>2)
// +4*(lane>>5) (m74/m101-verified).
__global__ __launch_bounds__(512, 1) void conv_kernel(const __hip_bfloat16* __restrict__ wbf,
                            const __hip_bfloat16* __restrict__ xsp,
                            const float* __restrict__ sc,
                            float* __restrict__ out) {
    __shared__ char lds[131072];   // buf c: A [256][64] at c*65536, B [256][64] at +32768

    // XCD chunking: 512 blocks, 64 consecutive logical ids per XCD (bijective, 512%8==0)
    const int bid = blockIdx.x;
    const int logical = (bid & 7) * 64 + (bid >> 3);
    const int m0 = (logical & 1) << 8;        // 0 / 256
    const int pt = (logical >> 1) & 15;       // pixel tile 0..15
    const int b  = logical >> 5;              // batch
    const int p0 = pt << 8;                   // 256 pixels = 4 image rows
    const int y0 = pt << 2;
    const int t = threadIdx.x;

    // --- staging mapping: LDS[row][c] = global[row][c ^ (row&7)] (conflict-free reads) ---
    const int r_base = t >> 3;                 // 0..63
    const int s_slot = (t & 7) ^ (r_base & 7);
    int pixoff[4];
#pragma unroll
    for (int i = 0; i < 4; ++i) {
        const int ri = i * 64 + r_base;        // pixel row in tile 0..255
        const int yy = y0 + (ri >> 6);         // un-shifted padded row (tap adds ky)
        const int xx = ri & 63;
        pixoff[i] = (((b * PAD_W) + yy) * PAD_W + xx) * XS_PIX_STRIDE + s_slot * 8;
    }

    // --- compute mapping: 8 waves 2M x 4N, wave tile 128x64 ---
    const int wv = t >> 6;
    const int wm = (wv >> 2) * 128;
    const int wn = (wv & 3) * 64;
    const int lane = t & 63;
    const int ln31 = lane & 31;
    const int kg = lane >> 5;                  // k-group 0/1 (8 contiguous k each)

    f32x16 acc[4][2] = {};   // [m-tile (32 rows)][n-tile (32 cols)]
    frag8 bfr[2][4];         // [nt][ks 0..3], all read at phase 0, live whole K-tile
    frag8 af[2][2];          // A tiles mth0 (mt 0..1) x ks-in-half
    frag8 ag[2][2];          // A tiles mth1 (mt 2..3) x ks-in-half

#define GLL(SRC, DST) __builtin_amdgcn_global_load_lds(                               \
    (const __attribute__((address_space(1))) unsigned int*)(SRC),                     \
    (__attribute__((address_space(3))) unsigned int*)(DST), 16, 0, 0)

#define STAGE_A(J, HALF) do {                                                         \
    const int jA_ = (J);                                                              \
    const __hip_bfloat16* srcA_ = wbf + (jA_ >> 3) * 262144                           \
        + (size_t)(m0 + (HALF) * 128 + r_base) * 512 + ((jA_ & 7) << 6) + s_slot * 8; \
    char* dstA_ = lds + (jA_ & 1) * 65536 + (HALF) * 16384 + t * 16;                  \
    GLL(srcA_, dstA_);                                                                \
    GLL(srcA_ + 64 * 512, dstA_ + 8192);                                              \
} while (0)

#define STAGE_B(J, HALF) do {                                                         \
    const int jB_ = (J);                                                              \
    const int kkB_ = jB_ >> 3;                                                        \
    const __hip_bfloat16* srcB_ = xsp + ((kkB_ / 3) * PAD_W + (kkB_ % 3)) * XS_PIX_STRIDE \
        + ((jB_ & 7) << 6);                                                           \
    char* dstB_ = lds + (jB_ & 1) * 65536 + 32768 + (HALF) * 16384 + t * 16;          \
    GLL(srcB_ + pixoff[(HALF) * 2 + 0], dstB_);                                       \
    GLL(srcB_ + pixoff[(HALF) * 2 + 1], dstB_ + 8192);                                \
} while (0)

// B frags: lane holds col=wn+nt*32+ln31, k = ks*16 + kg*8 .. +8 (16B contiguous)
#define RD_B_ALL(CUR) do {                                                            \
    const short* Bp_ = (const short*)(lds + (CUR) * 65536 + 32768);                   \
    _Pragma("unroll")                                                                 \
    for (int nt = 0; nt < 2; ++nt) {                                                  \
        const int R_ = wn + nt * 32 + ln31;                                           \
        _Pragma("unroll")                                                             \
        for (int ks = 0; ks < 4; ++ks)                                                \
            bfr[nt][ks] = *(const frag8*)(Bp_ + R_ * 64 + ((((ks * 2 + kg)) ^ (R_ & 7)) << 3)); \
    }                                                                                 \
} while (0)

// A frags for half MTH (tiles MTH*2+0, MTH*2+1), k-half KSH (ks KSH*2+0, KSH*2+1)
#define RD_A22(CUR, KSH, MTH, DST) do {                                               \
    const short* Ap_ = (const short*)(lds + (CUR) * 65536);                           \
    _Pragma("unroll")                                                                 \
    for (int mt = 0; mt < 2; ++mt) {                                                  \
        const int R_ = wm + ((MTH) * 2 + mt) * 32 + ln31;                             \
        _Pragma("unroll")                                                             \
        for (int ks = 0; ks < 2; ++ks) {                                              \
            const int ksg_ = (KSH) * 2 + ks;                                          \
            (DST)[mt][ks] = *(const frag8*)(Ap_ + R_ * 64 + (((ksg_ * 2 + kg) ^ (R_ & 7)) << 3)); \
        }                                                                             \
    }                                                                                 \
} while (0)

// 8 MFMA: (2 mt x 2 nt) x 2 ks; ks outer -> 4 independent MFMAs between dependents
#define MFMA_Q(AF, MTH, KSH) do {                                                     \
    __builtin_amdgcn_s_setprio(1);                                                    \
    _Pragma("unroll")                                                                 \
    for (int ks = 0; ks < 2; ++ks)                                                    \
        _Pragma("unroll")                                                             \
        for (int mt = 0; mt < 2; ++mt)                                                \
            _Pragma("unroll")                                                         \
            for (int nt = 0; nt < 2; ++nt)                                            \
                acc[(MTH) * 2 + mt][nt] = __builtin_amdgcn_mfma_f32_32x32x16_bf16(    \
                    (AF)[mt][ks], bfr[nt][(KSH) * 2 + ks], acc[(MTH) * 2 + mt][nt], 0, 0, 0); \
    __builtin_amdgcn_s_setprio(0);                                                    \
} while (0)

#define BAR __builtin_amdgcn_s_barrier()
#define LG8 asm volatile("s_waitcnt lgkmcnt(8)" ::: "memory")
#define LGKM0 do { asm volatile("s_waitcnt lgkmcnt(0)" ::: "memory");                 \
                   __builtin_amdgcn_sched_barrier(0); } while (0)
#define VM6 asm volatile("s_waitcnt vmcnt(6)" ::: "memory")
#define VM0 asm volatile("s_waitcnt vmcnt(0)" ::: "memory")

// K-tile J in buffer CUR. Stage schedule (steady): ph0: A1(J+1); ph1: B0(J+2);
// ph2: B1(J+2); ph3: A0(J+2). Region safety: B(J) fully read ph0; A(J) fully read
// ph2. vmcnt(6) at ph3 completes A1(J+1)+older, leaves B(J+2)+A0(J+2) in flight.
#define KTILE(J, CUR, SP1, SP2, VMC) do {                                             \
    /* phase 0: B all (8) + A mth0 ks01 (4) = 12 reads */                             \
    RD_B_ALL(CUR);                                                                    \
    RD_A22(CUR, 0, 0, af);                                                            \
    if (SP1) STAGE_A((J) + 1, 1);                                                     \
    LG8; BAR; LGKM0; MFMA_Q(af, 0, 0); BAR;                                           \
    /* phase 1: A mth1 ks01 (4 reads) */                                              \
    RD_A22(CUR, 0, 1, ag);                                                            \
    if (SP2) STAGE_B((J) + 2, 0);                                                     \
    BAR; LGKM0; MFMA_Q(ag, 1, 0); BAR;                                                \
    /* phase 2: A mth0+mth1 ks23 (8 reads) */                                         \
    RD_A22(CUR, 1, 0, af);                                                            \
    RD_A22(CUR, 1, 1, ag);                                                            \
    if (SP2) STAGE_B((J) + 2, 1);                                                     \
    BAR; LGKM0; MFMA_Q(af, 0, 1); BAR;                                                \
    /* phase 3: no reads */                                                           \
    if (SP2) STAGE_A((J) + 2, 0);                                                     \
    VMC; BAR; MFMA_Q(ag, 1, 1); BAR;                                                  \
} while (0)

    // prologue: 7 halves (K-tile 0 complete + K-tile 1 minus A1); vmcnt(6) forces k0 done
    STAGE_B(0, 0); STAGE_B(0, 1); STAGE_A(0, 0); STAGE_A(0, 1);
    STAGE_B(1, 0); STAGE_B(1, 1); STAGE_A(1, 0);
    VM6; BAR;

    for (int j = 0; j < 70; j += 2) {
        KTILE(j, 0, 1, 1, VM6);
        KTILE(j + 1, 1, 1, 1, VM6);
    }
    KTILE(70, 0, 1, 0, VM0);       // stages only A1(71); drain to it
    KTILE(71, 1, 0, 0, (void)0);   // pure compute

#undef KTILE
#undef VM0
#undef VM6
#undef LGKM0
#undef LG8
#undef BAR
#undef MFMA_Q
#undef RD_A22
#undef RD_B_ALL
#undef STAGE_B
#undef STAGE_A
#undef GLL

    // ---- epilogue: scale by G*demod[b][o], store fp32 NCHW ----
    // C/D 32x32 layout: col=lane&31, row=(reg&3)+8*(reg>>2)+4*(lane>>5)
    const float* scb = sc + b * 512;
    float* outb = out + (size_t)b * 512 * 4096;
#pragma unroll
    for (int mt = 0; mt < 4; ++mt) {
#pragma unroll
        for (int nt = 0; nt < 2; ++nt) {
#pragma unroll
            for (int reg = 0; reg < 16; ++reg) {
                const int rowf = (reg & 3) + 8 * (reg >> 2) + 4 * kg;
                const int mrow = m0 + wm + mt * 32 + rowf;
                outb[(size_t)mrow * 4096 + p0 + wn + nt * 32 + ln31] =
                    acc[mt][nt][reg] * scb[mrow];
            }
        }
    }
}

extern "C" void kernel_launch(void* const* d_in, const int* in_sizes, int n_in,
                              void* d_out, int out_size, void* d_ws, size_t ws_size,
                              hipStream_t stream) {
    (void)in_sizes; (void)n_in; (void)out_size; (void)ws_size;
    const float* x      = (const float*)d_in[0];
    const float* w      = (const float*)d_in[1];
    const float* weight = (const float*)d_in[2];
    const float* mw     = (const float*)d_in[3];
    const float* mb     = (const float*)d_in[4];
    float* out = (float*)d_out;

    char* ws = (char*)d_ws;
    float* style         = (float*)(ws + 0);        //  32 KB
    float* sc            = (float*)(ws + 32768);    //  32 KB
    float* wsq           = (float*)(ws + 65536);    //   1 MB
    __hip_bfloat16* wbf  = (__hip_bfloat16*)(ws + 1114112);  // 4.5 MB  [9][512][512]
    __hip_bfloat16* xsp  = (__hip_bfloat16*)(ws + 5832704);  // 68 MB   [16][66][66][512]

    wprep_kernel<<<dim3(1024), dim3(256), 0, stream>>>(weight, wsq, wbf);
    style_kernel<<<dim3(2048), dim3(256), 0, stream>>>(w, mw, mb, style);
    demod_kernel<<<dim3(2048), dim3(256), 0, stream>>>(style, wsq, sc);
    xs_kernel<<<dim3(65, 4, BATCH), dim3(256), 0, stream>>>(x, style, xsp);
    conv_kernel<<<dim3(512), dim3(512), 0, stream>>>(wbf, xsp, sc, out);
}